// Round 3
// baseline (369.300 us; speedup 1.0000x reference)
//
#include <hip/hip_runtime.h>
#include <stddef.h>

// Problem constants: B=32, T=4096, D=512, G=8, OUT=512
#define B_    32
#define T_    4096
#define D_    512
#define G_    8
#define OUT_  512
#define TC_   16              // token chunks over T
#define CHUNK_ 256            // tokens per chunk (2 per thread)

typedef float f4 __attribute__((ext_vector_type(4)));

// ---------------------------------------------------------------------------
// k1: compact-then-stream segmented partial sums.
// Block = (chunk tc, batch b), 128 threads (2 waves); each thread owns a
// float4 slice of D (128*4 = 512). Phase 1: coalesced mask+type read,
// ballot compaction of the chunk's 256 tokens into an LDS list (order is
// irrelevant for a sum). List is padded to a multiple of 8 with trash-tagged
// entries so phase 2 is a fixed unroll-8 loop: 8 row loads always in flight,
// SALU-only addressing (row index is readfirstlane'd), uniform switch on the
// group tag.
// ---------------------------------------------------------------------------
__global__ __launch_bounds__(128) void k1_partials(
    const float* __restrict__ batch, const int* __restrict__ types,
    const void* __restrict__ mask, float* __restrict__ partials,
    int* __restrict__ cpart)
{
    const int tc   = blockIdx.x;
    const int b    = blockIdx.y;
    const int tid  = threadIdx.x;
    const int lane = tid & 63;
    const int w    = tid >> 6;

    // --- mask dtype detection (bool may arrive as uint8 or int32) ---
    const int* mi = (const int*)mask;
    unsigned big = 0;
    #pragma unroll
    for (int i = 0; i < 64; ++i) big |= (unsigned)mi[i];
    const bool is_u8 = (big > 1u);
    const unsigned char* m8 = (const unsigned char*)mask;

    // --- phase 1: compaction ---
    const int t0 = tc * CHUNK_;
    const int tA = t0 + tid, tB = t0 + 128 + tid;
    const int gA = types[tA], gB = types[tB];
    const bool vA = !(is_u8 ? (m8[(size_t)b * T_ + tA] != 0)
                            : (mi[(size_t)b * T_ + tA] != 0));
    const bool vB = !(is_u8 ? (m8[(size_t)b * T_ + tB] != 0)
                            : (mi[(size_t)b * T_ + tB] != 0));

    __shared__ int list[CHUNK_ + 8];
    __shared__ int wcnt[4];

    const unsigned long long balA = __ballot(vA);
    const unsigned long long balB = __ballot(vB);
    if (lane == 0) { wcnt[w] = __popcll(balA); wcnt[2 + w] = __popcll(balB); }
    __syncthreads();

    const int base01 = wcnt[0];
    const int base10 = wcnt[0] + wcnt[1];
    const int base11 = base10 + wcnt[2];
    const int nvalid = base11 + wcnt[3];
    const unsigned long long lt = (1ull << lane) - 1ull;

    if (vA) list[(w ? base01 : 0) + __popcll(balA & lt)] = tid | (gA << 9);
    if (vB) list[(w ? base11 : base10) + __popcll(balB & lt)] = (128 + tid) | (gB << 9);

    const int rounded = (nvalid + 7) & ~7;
    if (tid < rounded - nvalid) list[nvalid + tid] = (8 << 9);  // trash tag
    __syncthreads();

    // --- phase 2: dense streaming accumulate ---
    f4 acc[G_]; f4 trash = (f4){0.f,0.f,0.f,0.f};
    int cnt[G_];
    #pragma unroll
    for (int g = 0; g < G_; ++g) { acc[g] = (f4){0.f,0.f,0.f,0.f}; cnt[g] = 0; }

    const float* bp = batch + ((size_t)b * T_ + (size_t)t0) * D_ + (tid << 2);

    #define ACC8(V, E) do {                                               \
        switch ((E) >> 9) {                                               \
            case 0: acc[0] += (V); cnt[0]++; break;                       \
            case 1: acc[1] += (V); cnt[1]++; break;                       \
            case 2: acc[2] += (V); cnt[2]++; break;                       \
            case 3: acc[3] += (V); cnt[3]++; break;                       \
            case 4: acc[4] += (V); cnt[4]++; break;                       \
            case 5: acc[5] += (V); cnt[5]++; break;                       \
            case 6: acc[6] += (V); cnt[6]++; break;                       \
            case 7: acc[7] += (V); cnt[7]++; break;                       \
            default: trash += (V); break;                                 \
        }                                                                 \
    } while (0)

    for (int j = 0; j < rounded; j += 8) {
        const int e0 = __builtin_amdgcn_readfirstlane(list[j + 0]);
        const int e1 = __builtin_amdgcn_readfirstlane(list[j + 1]);
        const int e2 = __builtin_amdgcn_readfirstlane(list[j + 2]);
        const int e3 = __builtin_amdgcn_readfirstlane(list[j + 3]);
        const int e4 = __builtin_amdgcn_readfirstlane(list[j + 4]);
        const int e5 = __builtin_amdgcn_readfirstlane(list[j + 5]);
        const int e6 = __builtin_amdgcn_readfirstlane(list[j + 6]);
        const int e7 = __builtin_amdgcn_readfirstlane(list[j + 7]);
        f4 v0 = *(const f4*)(bp + (size_t)(e0 & 511) * D_);
        f4 v1 = *(const f4*)(bp + (size_t)(e1 & 511) * D_);
        f4 v2 = *(const f4*)(bp + (size_t)(e2 & 511) * D_);
        f4 v3 = *(const f4*)(bp + (size_t)(e3 & 511) * D_);
        f4 v4 = *(const f4*)(bp + (size_t)(e4 & 511) * D_);
        f4 v5 = *(const f4*)(bp + (size_t)(e5 & 511) * D_);
        f4 v6 = *(const f4*)(bp + (size_t)(e6 & 511) * D_);
        f4 v7 = *(const f4*)(bp + (size_t)(e7 & 511) * D_);
        ACC8(v0, e0); ACC8(v1, e1); ACC8(v2, e2); ACC8(v3, e3);
        ACC8(v4, e4); ACC8(v5, e5); ACC8(v6, e6); ACC8(v7, e7);
    }
    #undef ACC8

    float* pp = partials + ((size_t)(tc * B_ + b) * G_) * D_ + (tid << 2);
    #pragma unroll
    for (int g = 0; g < G_; ++g)
        *(f4*)(pp + (size_t)g * D_) = acc[g];

    if (tid == 0) {
        int* cp = cpart + (tc * B_ + b) * G_;
        #pragma unroll
        for (int g = 0; g < G_; ++g) cp[g] = cnt[g];
    }
}

// ---------------------------------------------------------------------------
// k2a: reduce over TC chunks -> means[b,g,:]. Grid (G,B), 128 threads.
// ---------------------------------------------------------------------------
__global__ __launch_bounds__(128) void k2a_means(
    const float* __restrict__ partials, const int* __restrict__ cpart,
    float* __restrict__ means)
{
    const int g = blockIdx.x, b = blockIdx.y, tid = threadIdx.x;

    int cnt = 0;
    #pragma unroll
    for (int tc = 0; tc < TC_; ++tc) cnt += cpart[(tc * B_ + b) * G_ + g];

    f4 s = (f4){0.f,0.f,0.f,0.f};
    #pragma unroll
    for (int tc = 0; tc < TC_; ++tc)
        s += *(const f4*)(partials + ((size_t)(tc * B_ + b) * G_ + g) * D_ + (tid << 2));

    f4 m = (f4){0.f,0.f,0.f,0.f};
    if (cnt > 0) m = s * (1.0f / (float)cnt);
    *(f4*)(means + ((size_t)b * G_ + g) * D_ + (tid << 2)) = m;
}

// ---------------------------------------------------------------------------
// k2bc: out[b,g,o] = means[b,g,:] @ W[g,:,o] + bias[g,o], fused over full D.
// Grid (OC=8, BQ=4, G=8) = 256 blocks, 256 threads (4 waves).
// Block stages means[b0..b0+7][g][:] (16 KB) in LDS; wave w owns b rows
// {w*2, w*2+1}; lanes cover o = oc*64+lane. W is read once per bq (4x total,
// L2/L3-resident after first touch).
// ---------------------------------------------------------------------------
__global__ __launch_bounds__(256) void k2bc_gemm(
    const float* __restrict__ means, const float* __restrict__ W,
    const float* __restrict__ bias, float* __restrict__ out)
{
    const int oc = blockIdx.x, bq = blockIdx.y, g = blockIdx.z;
    const int tid = threadIdx.x, lane = tid & 63, w = tid >> 6;
    const int b0 = bq * 8;

    __shared__ float mlds[8][D_];
    #pragma unroll
    for (int i = 0; i < 4; ++i) {
        const int idx = i * 256 + tid;      // 0..1023 (f4 units)
        const int row = idx >> 7;
        const int c4  = idx & 127;
        *(f4*)&mlds[row][c4 << 2] =
            *(const f4*)(means + ((size_t)(b0 + row) * G_ + g) * D_ + (c4 << 2));
    }
    __syncthreads();

    const int o = oc * 64 + lane;
    const float* wp = W + ((size_t)g * D_) * OUT_ + o;
    const int r0 = w * 2, r1 = r0 + 1;
    float a0 = 0.f, a1 = 0.f;

    #pragma unroll 4
    for (int d0 = 0; d0 < D_; d0 += 4) {
        const float w0 = wp[(size_t)(d0 + 0) * OUT_];
        const float w1 = wp[(size_t)(d0 + 1) * OUT_];
        const float w2 = wp[(size_t)(d0 + 2) * OUT_];
        const float w3 = wp[(size_t)(d0 + 3) * OUT_];
        const f4 m0 = *(const f4*)&mlds[r0][d0];
        const f4 m1 = *(const f4*)&mlds[r1][d0];
        a0 += m0.x * w0; a0 += m0.y * w1; a0 += m0.z * w2; a0 += m0.w * w3;
        a1 += m1.x * w0; a1 += m1.y * w1; a1 += m1.z * w2; a1 += m1.w * w3;
    }

    const float bv = bias[g * OUT_ + o];
    out[((size_t)(b0 + r0) * G_ + g) * OUT_ + o] = a0 + bv;
    out[((size_t)(b0 + r1) * G_ + g) * OUT_ + o] = a1 + bv;
}

// ---------------------------------------------------------------------------
extern "C" void kernel_launch(void* const* d_in, const int* in_sizes, int n_in,
                              void* d_out, int out_size, void* d_ws, size_t ws_size,
                              hipStream_t stream)
{
    const float* batch = (const float*)d_in[0];   // [B,T,D] f32
    const float* W     = (const float*)d_in[1];   // [G,D,OUT] f32
    const float* bias  = (const float*)d_in[2];   // [G,OUT] f32
    const int*   types = (const int*)d_in[3];     // [T] i32
    const void*  mask  = d_in[4];                 // [B,T] bool (u8/i32 detected)
    float* out = (float*)d_out;                   // [B,G,OUT] f32

    float* ws = (float*)d_ws;
    const size_t P = (size_t)TC_ * B_ * G_ * D_;         // 2,097,152 floats
    float* partials = ws;
    int*   cpart    = (int*)(ws + P);                    // TC*B*G ints
    float* means    = ws + P + (size_t)TC_ * B_ * G_;    // B*G*D floats

    k1_partials<<<dim3(TC_, B_), 128, 0, stream>>>(batch, types, mask, partials, cpart);
    k2a_means  <<<dim3(G_, B_), 128, 0, stream>>>(partials, cpart, means);
    k2bc_gemm  <<<dim3(OUT_ / 64, B_ / 8, G_), 256, 0, stream>>>(means, W, bias, out);
}